// Round 15
// baseline (205.443 us; speedup 1.0000x reference)
//
#include <hip/hip_runtime.h>
#include <math.h>

#define N_NODES  100000
#define N_EDGES  800000
#define F        64
#define N_GRAPHS 64
#define NQUADS   25000       // N_NODES/4 exactly
#define ROWB     128         // bytes per hs row (64 * bf16)
#define COLCAP   3500000     // col slots cap (bound: 4*sum(deg)+12/quad = 3.5M worst case)
#define SENT     (N_NODES * ROWB)
#define FILLB    3125        // fill blocks in k_fillpx ((E+255)/256)

typedef _Float16 half8 __attribute__((ext_vector_type(8)));
typedef float    f32x4 __attribute__((ext_vector_type(4)));

// ---------------- workspace layout (bytes) ----------------
#define OFF_BUFA 0u           // ushort[(N+1)*F] 12,800,128 (row N = zero sentinel)
#define OFF_BUFB 12800256u    // ushort[(N+1)*F] 12,800,128
#define OFF_DIS  25600512u    // float[N]       400,000
#define OFF_DEG  26000512u    // int[N]         400,000
#define OFF_QI   26400512u    // int[2*NQUADS]  200,000 (per-quad {base,count})
#define OFF_TOT  26600576u    // int[1] allocator counter (pad 64)
#define OFF_COL  26600640u    // int[3.5M]   14,000,000 (padded+interleaved BYTE offsets)
#define OFF_WT   40600640u    // _Float16[3*4096] 24,576
#define OFF_RANK 40625216u    // int[E]       3,200,000
// total ~43.8 MB

__device__ inline ushort f2bf(float f) {               // round-to-nearest-even
    uint u = __float_as_uint(f);
    u = (u + 0x7FFFu + ((u >> 16) & 1u)) >> 16;
    return (ushort)u;
}
__device__ inline float bf2f(ushort s) {
    return __uint_as_float(((uint)s) << 16);
}

__device__ inline void atomicMaxFloat(float* addr, float v) {
    if (v >= 0.f) atomicMax((int*)addr, __float_as_int(v));
    else          atomicMin((unsigned int*)addr, __float_as_uint(v));
}

// Dependency-free init: zero degcnt + allocator, build f16 transposed weights,
// zero hs sentinel rows, init pool output to -INF. (col sentinels now written
// by k_quad into exactly the allocated ranges -- saves ~9MB of writes.)
__global__ void k_init(const float* __restrict__ W1, const float* __restrict__ W2,
                       const float* __restrict__ W3, _Float16* __restrict__ Wt,
                       ushort* __restrict__ bufA, ushort* __restrict__ bufB,
                       float* __restrict__ out, int* __restrict__ degcnt,
                       int* __restrict__ total) {
    int tid = blockIdx.x * blockDim.x + threadIdx.x;
    int stride = gridDim.x * blockDim.x;
    for (int i = tid; i < N_NODES; i += stride) degcnt[i] = 0;
    if (tid == 0) *total = 0;
    if (tid < 3 * 4096) {
        int wsel = tid >> 12, i = tid & 4095;
        int k = i >> 6, f = i & 63;
        const float* Ws = (wsel == 0) ? W1 : (wsel == 1) ? W2 : W3;
        Wt[wsel * 4096 + f * 64 + k] = (_Float16)Ws[k * 64 + f];
    } else if (tid < 3 * 4096 + 64) {
        int f = tid - 3 * 4096;
        bufA[(size_t)N_NODES * F + f] = 0;
        bufB[(size_t)N_NODES * F + f] = 0;
    } else if (tid < 3 * 4096 + 64 + N_GRAPHS * F) {
        out[tid - (3 * 4096 + 64)] = -INFINITY;
    }
}

// degree count AND per-edge rank (return value of the atomic we already pay)
__global__ void k_degree(const int* __restrict__ dst, int* __restrict__ degcnt,
                         int* __restrict__ rank) {
    int e = blockIdx.x * blockDim.x + threadIdx.x;
    if (e < N_EDGES) rank[e] = atomicAdd(&degcnt[dst[e]], 1);
}

// per-QUAD: dis for 4 nodes; padded quad slots = 4*ceil(maxdeg/4); slot range
// allocated via atomicAdd; quad sentinels its own range (adjacent threads own
// adjacent-ish ranges -> reasonably coalesced).
__global__ void k_quad(const int* __restrict__ degcnt, int* __restrict__ qinfo,
                       int* __restrict__ total, float* __restrict__ dis,
                       int* __restrict__ col) {
    int q = blockIdx.x * blockDim.x + threadIdx.x;
    if (q < NQUADS) {
        const int4 d4 = *(const int4*)(degcnt + q * 4);
        float4 dv;
        dv.x = rsqrtf((float)d4.x + 1.0f);
        dv.y = rsqrtf((float)d4.y + 1.0f);
        dv.z = rsqrtf((float)d4.z + 1.0f);
        dv.w = rsqrtf((float)d4.w + 1.0f);
        *(float4*)(dis + q * 4) = dv;
        int m = max(max(d4.x, d4.y), max(d4.z, d4.w));
        int P = (m + 3) & ~3;          // per-node padded length (multiple of 4)
        int tot = 4 * P;               // quad slots (multiple of 16)
        int base = atomicAdd(total, tot);
        qinfo[2 * q]     = base;
        qinfo[2 * q + 1] = tot;
        int4 s4 = make_int4(SENT, SENT, SENT, SENT);
        for (int i = 0; i < tot; i += 4)
            *(int4*)(col + base + i) = s4;
    }
}

// fill (blocks 0..FILLB-1) || prepx (remaining blocks). Both depend only on
// degree/quad outputs and are mutually independent.
// fill:  edge (src,dst,rank) -> col[qinfo[2*(dst/4)] + rank*4 + (dst&3)] = src*ROWB
// prepx: xs = bf16(dis * x)  (8 elems/thread)
__global__ void k_fillpx(const int* __restrict__ src, const int* __restrict__ dst,
                         const int* __restrict__ qinfo, const int* __restrict__ rank,
                         int* __restrict__ col, const float* __restrict__ x,
                         const float* __restrict__ dis, ushort* __restrict__ xs) {
    if (blockIdx.x < FILLB) {
        int e = blockIdx.x * 256 + threadIdx.x;
        if (e < N_EDGES) {
            int d = dst[e];
            col[qinfo[2 * (d >> 2)] + rank[e] * 4 + (d & 3)] = src[e] * ROWB;
        }
    } else {
        int t = (blockIdx.x - FILLB) * 256 + threadIdx.x;
        if (t < N_NODES * 8) {
            int n = t >> 3;
            float d = dis[n];
            const float4* px = (const float4*)(x + (size_t)t * 8);
            float4 a = px[0], b = px[1];
            ushort o[8] = { f2bf(d*a.x), f2bf(d*a.y), f2bf(d*a.z), f2bf(d*a.w),
                            f2bf(d*b.x), f2bf(d*b.y), f2bf(d*b.z), f2bf(d*b.w) };
            *(uint4*)(xs + (size_t)t * 8) = *(const uint4*)o;
        }
    }
}

// Fused GCN layer (agg-first, padded-CSR, scalar-pipe addressing):
//   g[n] = dis[n]*( hs[n] + sum_{e:dst=n} hs[src] )   (hs pre-scaled by dis; f16 LDS)
//   h'   = relu( g[n]·W + b )
//   POOL=false: out = bf16( SCALE ? dis*h' : h' ) -> hout
//   POOL=true : global-max-pool h' into out[graph][f] (batch sorted; LDS tile
//               pl[4][64], int-trick LDS atomics; rel>=4 falls back to global).
// Block = 64 nodes, 4 waves; wave owns rows [16w,16w+16) = 4 quads; phase 1/2
// barrier-free (wave-private LDS strip); POOL adds one barrier pair at the end.
// B-fragments (Wt) loaded up-front so their vmem issues overlap the gathers.
template<bool RELU, bool SCALE, bool POOL>
__global__ __launch_bounds__(256) void k_layer(const ushort* __restrict__ hs,
                                               const int* __restrict__ qinfo,
                                               const int* __restrict__ col,
                                               const float* __restrict__ dis,
                                               const _Float16* __restrict__ Wt,
                                               const float* __restrict__ bias,
                                               ushort* __restrict__ hout,
                                               const int* __restrict__ batch,
                                               float* __restrict__ out) {
    __shared__ _Float16 g[64 * 64];
    __shared__ float pl[4 * 64];
    int lane = threadIdx.x & 63;
    int w    = __builtin_amdgcn_readfirstlane(threadIdx.x >> 6);
    int chunk = blockIdx.x * 64;
    int wr16 = w * 16;
    int nbase = chunk + wr16;
    const char* hsb = (const char*)hs;
    int l2 = lane << 1;                      // shared per-lane byte offset
    int l15 = lane & 15, lh = lane >> 4;

    if (POOL) pl[threadIdx.x] = -INFINITY;

    // hoisted B-fragment loads: issue before the gather stream
    half8 bfrag[2][4];
#pragma unroll
    for (int ks = 0; ks < 2; ++ks)
#pragma unroll
        for (int nt = 0; nt < 4; ++nt)
            bfrag[ks][nt] = *(const half8*)(Wt + (nt * 16 + l15) * 64 + ks * 32 + lh * 8);

    // ---------- phase 1: aggregate 16 nodes (4 quads) ----------
    for (int p = 0; p < 4; ++p) {
        int na = nbase + 4 * p;              // first node of quad
        int quad = na >> 2;
        int rowb = wr16 + 4 * p;
        bool vq = quad < NQUADS;
        int qb0 = 0, iters = 0;
        if (vq) {
            qb0   = __builtin_amdgcn_readfirstlane(qinfo[2 * quad]);
            iters = __builtin_amdgcn_readfirstlane(qinfo[2 * quad + 1]) >> 4;
        }
        float a0 = vq ? bf2f(hs[(size_t)(na    ) * F + lane]) : 0.f;
        float a1 = vq ? bf2f(hs[(size_t)(na + 1) * F + lane]) : 0.f;
        float a2 = vq ? bf2f(hs[(size_t)(na + 2) * F + lane]) : 0.f;
        float a3 = vq ? bf2f(hs[(size_t)(na + 3) * F + lane]) : 0.f;
        const int* cp0 = col + qb0;
        for (int i = 0; i < iters; ++i) {
            const int* cp = cp0 + (i << 4);  // uniform addr -> s_load_dwordx16
            float v0  = bf2f(*(const ushort*)(hsb + (uint)cp[0]  + l2));
            float v1  = bf2f(*(const ushort*)(hsb + (uint)cp[1]  + l2));
            float v2  = bf2f(*(const ushort*)(hsb + (uint)cp[2]  + l2));
            float v3  = bf2f(*(const ushort*)(hsb + (uint)cp[3]  + l2));
            float v4  = bf2f(*(const ushort*)(hsb + (uint)cp[4]  + l2));
            float v5  = bf2f(*(const ushort*)(hsb + (uint)cp[5]  + l2));
            float v6  = bf2f(*(const ushort*)(hsb + (uint)cp[6]  + l2));
            float v7  = bf2f(*(const ushort*)(hsb + (uint)cp[7]  + l2));
            float v8  = bf2f(*(const ushort*)(hsb + (uint)cp[8]  + l2));
            float v9  = bf2f(*(const ushort*)(hsb + (uint)cp[9]  + l2));
            float v10 = bf2f(*(const ushort*)(hsb + (uint)cp[10] + l2));
            float v11 = bf2f(*(const ushort*)(hsb + (uint)cp[11] + l2));
            float v12 = bf2f(*(const ushort*)(hsb + (uint)cp[12] + l2));
            float v13 = bf2f(*(const ushort*)(hsb + (uint)cp[13] + l2));
            float v14 = bf2f(*(const ushort*)(hsb + (uint)cp[14] + l2));
            float v15 = bf2f(*(const ushort*)(hsb + (uint)cp[15] + l2));
            a0 += v0 + v4 + v8  + v12;       // interleave: node j at slots j,4+j,8+j,12+j
            a1 += v1 + v5 + v9  + v13;
            a2 += v2 + v6 + v10 + v14;
            a3 += v3 + v7 + v11 + v15;
        }
        float d0 = vq ? dis[na]     : 0.f;
        float d1 = vq ? dis[na + 1] : 0.f;
        float d2 = vq ? dis[na + 2] : 0.f;
        float d3 = vq ? dis[na + 3] : 0.f;
        g[(rowb    ) * 64 + lane] = (_Float16)(d0 * a0);
        g[(rowb + 1) * 64 + lane] = (_Float16)(d1 * a1);
        g[(rowb + 2) * 64 + lane] = (_Float16)(d2 * a2);
        g[(rowb + 3) * 64 + lane] = (_Float16)(d3 * a3);
    }
    // no barrier: phase 2 reads only this wave's own strip (same-wave LDS ordering)

    // ---------- phase 2: C[16x64] = g_strip · W via MFMA ----------
    f32x4 acc4[4] = {};
#pragma unroll
    for (int ks = 0; ks < 2; ++ks) {
        half8 a = *(const half8*)(&g[(wr16 + l15) * 64 + ks * 32 + lh * 8]);
#pragma unroll
        for (int nt = 0; nt < 4; ++nt)
            acc4[nt] = __builtin_amdgcn_mfma_f32_16x16x32_f16(a, bfrag[ks][nt], acc4[nt], 0, 0, 0);
    }

    // ---------- epilogue ----------
    float bvals[4];
#pragma unroll
    for (int nt = 0; nt < 4; ++nt) bvals[nt] = bias[nt * 16 + l15];

    if (POOL) __syncthreads();   // pl init + all waves ready before LDS atomics
    int gmin = 0;
    if (POOL) gmin = __builtin_amdgcn_readfirstlane(batch[chunk]);

#pragma unroll
    for (int rr = 0; rr < 4; ++rr) {
        int row = wr16 + lh * 4 + rr;
        int ng = chunk + row;
        if (ng < N_NODES) {
            if (POOL) {
                int gb = batch[ng];
                int rel = gb - gmin;
#pragma unroll
                for (int nt = 0; nt < 4; ++nt) {
                    float vv = acc4[nt][rr] + bvals[nt];
                    if (RELU) vv = fmaxf(vv, 0.f);
                    if (rel < 4) atomicMaxFloat(&pl[rel * 64 + nt * 16 + l15], vv);
                    else         atomicMaxFloat(&out[gb * F + nt * 16 + l15], vv);
                }
            } else {
                float ds2 = 1.f;
                if (SCALE) ds2 = dis[ng];
#pragma unroll
                for (int nt = 0; nt < 4; ++nt) {
                    float vv = acc4[nt][rr] + bvals[nt];
                    if (RELU) vv = fmaxf(vv, 0.f);
                    if (SCALE) vv *= ds2;
                    hout[(size_t)ng * F + nt * 16 + l15] = f2bf(vv);
                }
            }
        }
    }
    if (POOL) {
        __syncthreads();
        float v = pl[threadIdx.x];
        int r = threadIdx.x >> 6, c = threadIdx.x & 63;
        int gg = gmin + r;
        if (v != -INFINITY && gg < N_GRAPHS)
            atomicMaxFloat(&out[gg * F + c], v);
    }
}

extern "C" void kernel_launch(void* const* d_in, const int* in_sizes, int n_in,
                              void* d_out, int out_size, void* d_ws, size_t ws_size,
                              hipStream_t stream) {
    const float* x     = (const float*)d_in[0];
    const int*   ei    = (const int*)d_in[1];
    const int*   batch = (const int*)d_in[2];
    const float* W1 = (const float*)d_in[3];
    const float* b1 = (const float*)d_in[4];
    const float* W2 = (const float*)d_in[5];
    const float* b2 = (const float*)d_in[6];
    const float* W3 = (const float*)d_in[7];
    const float* b3 = (const float*)d_in[8];
    const int* src = ei;
    const int* dst = ei + N_EDGES;

    char* ws = (char*)d_ws;
    ushort*   bufA   = (ushort*)(ws + OFF_BUFA);
    ushort*   bufB   = (ushort*)(ws + OFF_BUFB);
    float*    dis    = (float*)(ws + OFF_DIS);
    int*      degcnt = (int*)(ws + OFF_DEG);
    int*      qinfo  = (int*)(ws + OFF_QI);
    int*      total  = (int*)(ws + OFF_TOT);
    int*      col    = (int*)(ws + OFF_COL);
    _Float16* wt     = (_Float16*)(ws + OFF_WT);
    int*      rank   = (int*)(ws + OFF_RANK);
    float*    out    = (float*)d_out;

    // 1) dependency-free init (degcnt, allocator, Wt, sentinel rows, out=-INF)
    k_init<<<512, 256, 0, stream>>>(W1, W2, W3, wt, bufA, bufB, out, degcnt, total);
    // 2) degree + rank
    k_degree<<<(N_EDGES + 255) / 256, 256, 0, stream>>>(dst, degcnt, rank);
    // 3) dis + quad slot-range allocation + own-range sentinel fill
    k_quad<<<(NQUADS + 255) / 256, 256, 0, stream>>>(degcnt, qinfo, total, dis, col);
    // 4) fill || prepx
    k_fillpx<<<FILLB + (N_NODES * 8 + 255) / 256, 256, 0, stream>>>(src, dst, qinfo, rank, col, x, dis, bufA);

    const int LBLOCKS = (N_NODES + 63) / 64;   // 1563
    k_layer<true,  true,  false><<<LBLOCKS, 256, 0, stream>>>(bufA, qinfo, col, dis, wt,        b1, bufB, nullptr, nullptr);
    k_layer<true,  true,  false><<<LBLOCKS, 256, 0, stream>>>(bufB, qinfo, col, dis, wt + 4096, b2, bufA, nullptr, nullptr);
    k_layer<false, false, true ><<<LBLOCKS, 256, 0, stream>>>(bufA, qinfo, col, dis, wt + 8192, b3, bufB, batch, out);
}

// Round 16
// 155.893 us; speedup vs baseline: 1.3178x; 1.3178x over previous
//
#include <hip/hip_runtime.h>
#include <math.h>

#define N_NODES  100000
#define N_EDGES  800000
#define F        64
#define N_GRAPHS 64
#define NQUADS   25000       // N_NODES/4 exactly
#define ROWB     128         // bytes per hs row (64 * bf16)
#define COLCAP   3500000     // col slots; bound: 4*sum(maxdeg)+12/quad <= 3.5M
#define SENT     (N_NODES * ROWB)

typedef _Float16 half8 __attribute__((ext_vector_type(8)));
typedef float    f32x4 __attribute__((ext_vector_type(4)));

// ---------------- workspace layout (bytes) ----------------
#define OFF_BUFA 0u           // ushort[(N+1)*F] 12,800,128 (row N = zero sentinel)
#define OFF_BUFB 12800256u    // ushort[(N+1)*F] 12,800,128
#define OFF_DIS  25600512u    // float[N]       400,000
#define OFF_DEG  26000512u    // int[N]         400,000
#define OFF_QB   26400512u    // int[NQUADS+1]  100,004
#define OFF_BSUM 26500544u    // int[128]
#define OFF_COL  26501120u    // int[3.5M]   14,000,000 (padded+interleaved BYTE offsets)
#define OFF_WT   40501120u    // _Float16[3*4096] 24,576
#define OFF_RANK 40525696u    // int[E]       3,200,000
// total ~43.7 MB

__device__ inline ushort f2bf(float f) {               // round-to-nearest-even
    uint u = __float_as_uint(f);
    u = (u + 0x7FFFu + ((u >> 16) & 1u)) >> 16;
    return (ushort)u;
}
__device__ inline float bf2f(ushort s) {
    return __uint_as_float(((uint)s) << 16);
}

__device__ inline void atomicMaxFloat(float* addr, float v) {
    if (v >= 0.f) atomicMax((int*)addr, __float_as_int(v));
    else          atomicMin((unsigned int*)addr, __float_as_uint(v));
}

// One dependency-free init kernel: sentinel whole col region (coalesced sweep),
// zero degcnt, build f16 transposed weights, zero hs sentinel rows, init pool out.
__global__ void k_init(const float* __restrict__ W1, const float* __restrict__ W2,
                       const float* __restrict__ W3, _Float16* __restrict__ Wt,
                       ushort* __restrict__ bufA, ushort* __restrict__ bufB,
                       float* __restrict__ out, int* __restrict__ degcnt,
                       int* __restrict__ col) {
    int tid = blockIdx.x * blockDim.x + threadIdx.x;
    int stride = gridDim.x * blockDim.x;
    for (int i = tid; i < COLCAP; i += stride) col[i] = SENT;
    for (int i = tid; i < N_NODES; i += stride) degcnt[i] = 0;
    if (tid < 3 * 4096) {
        int wsel = tid >> 12, i = tid & 4095;
        int k = i >> 6, f = i & 63;
        const float* Ws = (wsel == 0) ? W1 : (wsel == 1) ? W2 : W3;
        Wt[wsel * 4096 + f * 64 + k] = (_Float16)Ws[k * 64 + f];
    } else if (tid < 3 * 4096 + 64) {
        int f = tid - 3 * 4096;
        bufA[(size_t)N_NODES * F + f] = 0;
        bufB[(size_t)N_NODES * F + f] = 0;
    } else if (tid < 3 * 4096 + 64 + N_GRAPHS * F) {
        out[tid - (3 * 4096 + 64)] = -INFINITY;
    }
}

// degree count AND per-edge rank (return value of the atomic we already pay)
__global__ void k_degree(const int* __restrict__ dst, int* __restrict__ degcnt,
                         int* __restrict__ rank) {
    int e = blockIdx.x * blockDim.x + threadIdx.x;
    if (e < N_EDGES) rank[e] = atomicAdd(&degcnt[dst[e]], 1);
}

// per-QUAD: dis for 4 nodes; padded quad slots = 4*ceil(maxdeg/4);
// block-inclusive-scan -> qbase[q+1]; block totals -> bsum.
__global__ void k_quad(const int* __restrict__ degcnt, int* __restrict__ qbase,
                       int* __restrict__ bsum, float* __restrict__ dis) {
    __shared__ int s[1024];
    int q = blockIdx.x * 1024 + threadIdx.x;
    int tot = 0;
    if (q < NQUADS) {
        const int4 d4 = *(const int4*)(degcnt + q * 4);
        float4 dv;
        dv.x = rsqrtf((float)d4.x + 1.0f);
        dv.y = rsqrtf((float)d4.y + 1.0f);
        dv.z = rsqrtf((float)d4.z + 1.0f);
        dv.w = rsqrtf((float)d4.w + 1.0f);
        *(float4*)(dis + q * 4) = dv;
        int m = max(max(d4.x, d4.y), max(d4.z, d4.w));
        int P = (m + 3) & ~3;          // per-node padded length (multiple of 4)
        tot = 4 * P;                   // quad slots (multiple of 16)
    }
    s[threadIdx.x] = tot;
    __syncthreads();
    for (int off = 1; off < 1024; off <<= 1) {
        int t = (threadIdx.x >= off) ? s[threadIdx.x - off] : 0;
        __syncthreads();
        s[threadIdx.x] += t;
        __syncthreads();
    }
    if (q < NQUADS) qbase[q + 1] = s[threadIdx.x];
    if (threadIdx.x == 1023) bsum[blockIdx.x] = s[1023];
}

// merged: blocks 0..24 finish the qbase scan (each computes its own bsum prefix);
// blocks 25+ run prepx: xs = bf16(dis * x)  (needs only dis, from k_quad).
__global__ void k_scan3px(int* __restrict__ qbase, const int* __restrict__ bsum,
                          const float* __restrict__ x, const float* __restrict__ dis,
                          ushort* __restrict__ xs) {
    if (blockIdx.x < 25) {
        __shared__ int soff;
        if (threadIdx.x == 0) {
            int acc = 0;
            for (int j = 0; j < (int)blockIdx.x; ++j) acc += bsum[j];
            soff = acc;
        }
        __syncthreads();
        int off = soff;
        int q = blockIdx.x * 1024 + threadIdx.x;
        if (q < NQUADS) qbase[q + 1] += off;
        if (q == 0) qbase[0] = 0;
    } else {
        int t = (blockIdx.x - 25) * 1024 + threadIdx.x;
        if (t < N_NODES * 8) {
            int n = t >> 3;
            float d = dis[n];
            const float4* px = (const float4*)(x + (size_t)t * 8);
            float4 a = px[0], b = px[1];
            ushort o[8] = { f2bf(d*a.x), f2bf(d*a.y), f2bf(d*a.z), f2bf(d*a.w),
                            f2bf(d*b.x), f2bf(d*b.y), f2bf(d*b.z), f2bf(d*b.w) };
            *(uint4*)(xs + (size_t)t * 8) = *(const uint4*)o;
        }
    }
}

// interleaved padded fill with BYTE offsets:
// edge (src,dst,rank) -> col[qbase[dst/4] + rank*4 + (dst&3)] = src*ROWB
__global__ void k_fill(const int* __restrict__ src, const int* __restrict__ dst,
                       const int* __restrict__ qbase, const int* __restrict__ rank,
                       int* __restrict__ col) {
    int e = blockIdx.x * blockDim.x + threadIdx.x;
    if (e < N_EDGES) {
        int d = dst[e];
        col[qbase[d >> 2] + rank[e] * 4 + (d & 3)] = src[e] * ROWB;
    }
}

// Fused GCN layer (agg-first, padded-CSR, scalar-pipe addressing):
//   g[n] = dis[n]*( hs[n] + sum_{e:dst=n} hs[src] )   (hs pre-scaled by dis; f16 LDS)
//   h'   = relu( g[n]·W + b )
//   POOL=false: out = bf16( SCALE ? dis*h' : h' ) -> hout
//   POOL=true : global-max-pool h' into out[graph][f] (batch sorted; LDS tile
//               pl[4][64], int-trick LDS atomics; rel>=4 falls back to global).
// Block = 64 nodes, 4 waves; wave owns rows [16w,16w+16) = 4 quads; phase 1/2
// barrier-free (wave-private LDS strip); POOL adds one barrier pair at the end.
template<bool RELU, bool SCALE, bool POOL>
__global__ __launch_bounds__(256) void k_layer(const ushort* __restrict__ hs,
                                               const int* __restrict__ qbase,
                                               const int* __restrict__ col,
                                               const float* __restrict__ dis,
                                               const _Float16* __restrict__ Wt,
                                               const float* __restrict__ bias,
                                               ushort* __restrict__ hout,
                                               const int* __restrict__ batch,
                                               float* __restrict__ out) {
    __shared__ _Float16 g[64 * 64];
    __shared__ float pl[4 * 64];
    int lane = threadIdx.x & 63;
    int w    = __builtin_amdgcn_readfirstlane(threadIdx.x >> 6);
    int chunk = blockIdx.x * 64;
    int wr16 = w * 16;
    int nbase = chunk + wr16;
    const char* hsb = (const char*)hs;
    int l2 = lane << 1;                      // shared per-lane byte offset

    if (POOL) pl[threadIdx.x] = -INFINITY;

    // ---------- phase 1: aggregate 16 nodes (4 quads) ----------
    for (int p = 0; p < 4; ++p) {
        int na = nbase + 4 * p;              // first node of quad
        int quad = na >> 2;
        int rowb = wr16 + 4 * p;
        bool vq = quad < NQUADS;
        int qb0 = 0, iters = 0;
        if (vq) {
            qb0   = __builtin_amdgcn_readfirstlane(qbase[quad]);
            int qb1 = __builtin_amdgcn_readfirstlane(qbase[quad + 1]);
            iters = (qb1 - qb0) >> 4;
        }
        float a0 = vq ? bf2f(hs[(size_t)(na    ) * F + lane]) : 0.f;
        float a1 = vq ? bf2f(hs[(size_t)(na + 1) * F + lane]) : 0.f;
        float a2 = vq ? bf2f(hs[(size_t)(na + 2) * F + lane]) : 0.f;
        float a3 = vq ? bf2f(hs[(size_t)(na + 3) * F + lane]) : 0.f;
        const int* cp0 = col + qb0;
        for (int i = 0; i < iters; ++i) {
            const int* cp = cp0 + (i << 4);  // uniform addr -> s_load_dwordx16
            float v0  = bf2f(*(const ushort*)(hsb + (uint)cp[0]  + l2));
            float v1  = bf2f(*(const ushort*)(hsb + (uint)cp[1]  + l2));
            float v2  = bf2f(*(const ushort*)(hsb + (uint)cp[2]  + l2));
            float v3  = bf2f(*(const ushort*)(hsb + (uint)cp[3]  + l2));
            float v4  = bf2f(*(const ushort*)(hsb + (uint)cp[4]  + l2));
            float v5  = bf2f(*(const ushort*)(hsb + (uint)cp[5]  + l2));
            float v6  = bf2f(*(const ushort*)(hsb + (uint)cp[6]  + l2));
            float v7  = bf2f(*(const ushort*)(hsb + (uint)cp[7]  + l2));
            float v8  = bf2f(*(const ushort*)(hsb + (uint)cp[8]  + l2));
            float v9  = bf2f(*(const ushort*)(hsb + (uint)cp[9]  + l2));
            float v10 = bf2f(*(const ushort*)(hsb + (uint)cp[10] + l2));
            float v11 = bf2f(*(const ushort*)(hsb + (uint)cp[11] + l2));
            float v12 = bf2f(*(const ushort*)(hsb + (uint)cp[12] + l2));
            float v13 = bf2f(*(const ushort*)(hsb + (uint)cp[13] + l2));
            float v14 = bf2f(*(const ushort*)(hsb + (uint)cp[14] + l2));
            float v15 = bf2f(*(const ushort*)(hsb + (uint)cp[15] + l2));
            a0 += v0 + v4 + v8  + v12;       // interleave: node j at slots j,4+j,8+j,12+j
            a1 += v1 + v5 + v9  + v13;
            a2 += v2 + v6 + v10 + v14;
            a3 += v3 + v7 + v11 + v15;
        }
        float d0 = vq ? dis[na]     : 0.f;
        float d1 = vq ? dis[na + 1] : 0.f;
        float d2 = vq ? dis[na + 2] : 0.f;
        float d3 = vq ? dis[na + 3] : 0.f;
        g[(rowb    ) * 64 + lane] = (_Float16)(d0 * a0);
        g[(rowb + 1) * 64 + lane] = (_Float16)(d1 * a1);
        g[(rowb + 2) * 64 + lane] = (_Float16)(d2 * a2);
        g[(rowb + 3) * 64 + lane] = (_Float16)(d3 * a3);
    }
    // no barrier: phase 2 reads only this wave's own strip (same-wave LDS ordering)

    // ---------- phase 2: C[16x64] = g_strip · W via MFMA ----------
    int l15 = lane & 15, lh = lane >> 4;
    half8 bfrag[2][4];
#pragma unroll
    for (int ks = 0; ks < 2; ++ks)
#pragma unroll
        for (int nt = 0; nt < 4; ++nt)
            bfrag[ks][nt] = *(const half8*)(Wt + (nt * 16 + l15) * 64 + ks * 32 + lh * 8);

    f32x4 acc4[4] = {};
#pragma unroll
    for (int ks = 0; ks < 2; ++ks) {
        half8 a = *(const half8*)(&g[(wr16 + l15) * 64 + ks * 32 + lh * 8]);
#pragma unroll
        for (int nt = 0; nt < 4; ++nt)
            acc4[nt] = __builtin_amdgcn_mfma_f32_16x16x32_f16(a, bfrag[ks][nt], acc4[nt], 0, 0, 0);
    }

    // ---------- epilogue ----------
    float bvals[4];
#pragma unroll
    for (int nt = 0; nt < 4; ++nt) bvals[nt] = bias[nt * 16 + l15];

    if (POOL) __syncthreads();   // pl init + all waves ready before LDS atomics
    int gmin = 0;
    if (POOL) gmin = __builtin_amdgcn_readfirstlane(batch[chunk]);

#pragma unroll
    for (int rr = 0; rr < 4; ++rr) {
        int row = wr16 + lh * 4 + rr;
        int ng = chunk + row;
        if (ng < N_NODES) {
            if (POOL) {
                int gb = batch[ng];
                int rel = gb - gmin;
#pragma unroll
                for (int nt = 0; nt < 4; ++nt) {
                    float vv = acc4[nt][rr] + bvals[nt];
                    if (RELU) vv = fmaxf(vv, 0.f);
                    if (rel < 4) atomicMaxFloat(&pl[rel * 64 + nt * 16 + l15], vv);
                    else         atomicMaxFloat(&out[gb * F + nt * 16 + l15], vv);
                }
            } else {
                float ds2 = 1.f;
                if (SCALE) ds2 = dis[ng];
#pragma unroll
                for (int nt = 0; nt < 4; ++nt) {
                    float vv = acc4[nt][rr] + bvals[nt];
                    if (RELU) vv = fmaxf(vv, 0.f);
                    if (SCALE) vv *= ds2;
                    hout[(size_t)ng * F + nt * 16 + l15] = f2bf(vv);
                }
            }
        }
    }
    if (POOL) {
        __syncthreads();
        float v = pl[threadIdx.x];
        int r = threadIdx.x >> 6, c = threadIdx.x & 63;
        int gg = gmin + r;
        if (v != -INFINITY && gg < N_GRAPHS)
            atomicMaxFloat(&out[gg * F + c], v);
    }
}

extern "C" void kernel_launch(void* const* d_in, const int* in_sizes, int n_in,
                              void* d_out, int out_size, void* d_ws, size_t ws_size,
                              hipStream_t stream) {
    const float* x     = (const float*)d_in[0];
    const int*   ei    = (const int*)d_in[1];
    const int*   batch = (const int*)d_in[2];
    const float* W1 = (const float*)d_in[3];
    const float* b1 = (const float*)d_in[4];
    const float* W2 = (const float*)d_in[5];
    const float* b2 = (const float*)d_in[6];
    const float* W3 = (const float*)d_in[7];
    const float* b3 = (const float*)d_in[8];
    const int* src = ei;
    const int* dst = ei + N_EDGES;

    char* ws = (char*)d_ws;
    ushort*   bufA   = (ushort*)(ws + OFF_BUFA);
    ushort*   bufB   = (ushort*)(ws + OFF_BUFB);
    float*    dis    = (float*)(ws + OFF_DIS);
    int*      degcnt = (int*)(ws + OFF_DEG);
    int*      qbase  = (int*)(ws + OFF_QB);
    int*      bsum   = (int*)(ws + OFF_BSUM);
    int*      col    = (int*)(ws + OFF_COL);
    _Float16* wt     = (_Float16*)(ws + OFF_WT);
    int*      rank   = (int*)(ws + OFF_RANK);
    float*    out    = (float*)d_out;

    // 1) dependency-free init (col sentinels, degcnt zero, Wt, hs sentinel rows, out=-INF)
    k_init<<<1024, 256, 0, stream>>>(W1, W2, W3, wt, bufA, bufB, out, degcnt, col);
    // 2) degree + rank
    k_degree<<<(N_EDGES + 255) / 256, 256, 0, stream>>>(dst, degcnt, rank);
    // 3) quad-padded sizes + dis + block scan
    k_quad<<<25, 1024, 0, stream>>>(degcnt, qbase, bsum, dis);
    // 4) finish scan (blocks 0..24) || prepx (blocks 25+)
    k_scan3px<<<25 + (N_NODES * 8 + 1023) / 1024, 1024, 0, stream>>>(qbase, bsum, x, dis, bufA);
    // 5) interleaved padded fill (byte offsets)
    k_fill<<<(N_EDGES + 255) / 256, 256, 0, stream>>>(src, dst, qbase, rank, col);

    const int LBLOCKS = (N_NODES + 63) / 64;   // 1563
    k_layer<true,  true,  false><<<LBLOCKS, 256, 0, stream>>>(bufA, qbase, col, dis, wt,        b1, bufB, nullptr, nullptr);
    k_layer<true,  true,  false><<<LBLOCKS, 256, 0, stream>>>(bufB, qbase, col, dis, wt + 4096, b2, bufA, nullptr, nullptr);
    k_layer<false, false, true ><<<LBLOCKS, 256, 0, stream>>>(bufA, qbase, col, dis, wt + 8192, b3, bufB, batch, out);
}